// Round 13
// baseline (49.280 us; speedup 1.0000x reference)
//
#include <hip/hip_runtime.h>
#include <math.h>

#define NB 16
#define NC 256
#define NH 64
#define NW 64
#define HALF 128
#define PLANE (NH*NW)   // 4096

// ws: attention map only
#define WS_ATT 0              // NB*NH*NW = 65536 floats

// d_out scratch (floats), all plain stores:
#define SCR_CONS 0                   // 8 slices x [b][h][w] = 524288 floats
#define SCR_GHP  524288              // [b*64+h]*8 + cg : 8192 floats
#define SCR_GWP  (524288 + 8192)     // [b*64+w]*128 + cg*16+hg : 131072 floats

__device__ __forceinline__ float sum4(float4 v) { return (v.x+v.y)+(v.z+v.w); }

// Block = (b, cg: 16 channel-pairs, hg: 4-row stripe). 2048 blocks = 8/CU,
// 32 waves/CU (k_apply's proven TLP regime). Wave v covers pairs cg*16+v*4+pl;
// lane = w4(4b)<<2 | pl(2b). Per thread: 6-iteration row loop, 2 independent
// float4 loads/iter, rolling 3-row product window in named regs, horizontal
// 3-tap via lane shuffles, pair-reduce via shfl_xor. ONE barrier (epilogue).
// Plain-store partials, zero atomics. Softmax in-prologue.
__global__ __launch_bounds__(256) void k_reduce(const float* __restrict__ x,
                                                const float* __restrict__ dwh,
                                                const float* __restrict__ dww,
                                                float* __restrict__ scr) {
    __shared__ float  ew[256], eh[256];       // exp(weights)
    __shared__ float  wsum[8];
    __shared__ float4 consacc[4][4][16];      // per-wave cons rows, 4 KB
    __shared__ float  ghacc[4][4];
    __shared__ float  gwacc[4][64];

    const int t    = threadIdx.x;
    const int v    = t >> 6;        // wave 0..3
    const int lane = t & 63;
    const int pl   = lane & 3;      // channel-pair lane
    const int w4   = lane >> 2;     // float4 col 0..15

    const int blk = blockIdx.x;
    const int hg  = blk & 15;           // 4-row stripe
    const int cg  = (blk >> 4) & 7;     // 16-pair group
    const int b   = blk >> 7;
    const int r0  = hg << 2;            // first owned row

    // ---- prologue: softmax denominators
    {
        const float vw = dww[t], vh = dwh[t];
        const float evw = expf(vw), evh = expf(vh);
        ew[t] = evw; eh[t] = evh;
        float sw = evw, sh = evh;
        #pragma unroll
        for (int m = 1; m < 64; m <<= 1) { sw += __shfl_xor(sw, m); sh += __shfl_xor(sh, m); }
        if (lane == 0) { wsum[v] = sw; wsum[4+v] = sh; }
    }
    __syncthreads();
    const float invSw = 1.f/((wsum[0]+wsum[1])+(wsum[2]+wsum[3]));
    const float invSh = 1.f/((wsum[4]+wsum[5])+(wsum[6]+wsum[7]));

    const int   c1  = cg*16 + v*4 + pl;
    const float ww1 = ew[c1]*invSw, ww2 = ew[c1+HALF]*invSw;
    const float wh1 = eh[c1]*invSh, wh2 = eh[c1+HALF]*invSh;

    const float* p1 = x + ((size_t)(b*NC + c1))*PLANE + w4*4;
    const float* p2 = p1 + (size_t)HALF*PLANE;

    // rolling product window (named regs -> no scratch)
    float4 w0 = {0,0,0,0}, w1 = {0,0,0,0}, w2 = {0,0,0,0};
    float4 colacc = {0,0,0,0};

    #pragma unroll
    for (int j = 0; j < 6; ++j) {
        const int r = r0 - 1 + j;                   // row to load
        float4 p = {0.f,0.f,0.f,0.f};
        const bool live = (j == 0) ? (r >= 0) : ((j == 5) ? (r < 64) : true);
        if (live) {
            const float4 x1 = *reinterpret_cast<const float4*>(p1 + r*NW);
            const float4 x2 = *reinterpret_cast<const float4*>(p2 + r*NW);
            p.x = x1.x*x2.x; p.y = x1.y*x2.y; p.z = x1.z*x2.z; p.w = x1.w*x2.w;
            if (j >= 1 && j <= 4) {                 // owned rows: gh/gw
                float g = ww1*sum4(x1) + ww2*sum4(x2);
                g += __shfl_xor(g,1);  g += __shfl_xor(g,2);  g += __shfl_xor(g,4);
                g += __shfl_xor(g,8);  g += __shfl_xor(g,16); g += __shfl_xor(g,32);
                if (lane == 0) ghacc[v][j-1] = g;
                colacc.x += wh1*x1.x + wh2*x2.x;
                colacc.y += wh1*x1.y + wh2*x2.y;
                colacc.z += wh1*x1.z + wh2*x2.z;
                colacc.w += wh1*x1.w + wh2*x2.w;
            }
        }
        w0 = w1; w1 = w2; w2 = p;
        if (j >= 2) {                               // emit cons row r0+j-2
            float4 vs;
            vs.x = w0.x+w1.x+w2.x; vs.y = w0.y+w1.y+w2.y;
            vs.z = w0.z+w1.z+w2.z; vs.w = w0.w+w1.w+w2.w;
            float L = __shfl_up(vs.w, 4);
            float R = __shfl_down(vs.x, 4);
            if (w4 == 0)  L = 0.f;
            if (w4 == 15) R = 0.f;
            float4 c;
            c.x = fabsf(L    + vs.x + vs.y);
            c.y = fabsf(vs.x + vs.y + vs.z);
            c.z = fabsf(vs.y + vs.z + vs.w);
            c.w = fabsf(vs.z + vs.w + R);
            c.x += __shfl_xor(c.x,1); c.x += __shfl_xor(c.x,2);
            c.y += __shfl_xor(c.y,1); c.y += __shfl_xor(c.y,2);
            c.z += __shfl_xor(c.z,1); c.z += __shfl_xor(c.z,2);
            c.w += __shfl_xor(c.w,1); c.w += __shfl_xor(c.w,2);
            if (pl == 0) consacc[v][j-2][w4] = c;
        }
    }

    // gw: reduce over pairs, stage per wave
    colacc.x += __shfl_xor(colacc.x,1); colacc.x += __shfl_xor(colacc.x,2);
    colacc.y += __shfl_xor(colacc.y,1); colacc.y += __shfl_xor(colacc.y,2);
    colacc.z += __shfl_xor(colacc.z,1); colacc.z += __shfl_xor(colacc.z,2);
    colacc.w += __shfl_xor(colacc.w,1); colacc.w += __shfl_xor(colacc.w,2);
    if (pl == 0) {
        gwacc[v][w4*4+0] = colacc.x;
        gwacc[v][w4*4+1] = colacc.y;
        gwacc[v][w4*4+2] = colacc.z;
        gwacc[v][w4*4+3] = colacc.w;
    }
    __syncthreads();   // the ONE barrier

    // ---- epilogue: cross-wave sums, plain stores
    const float SC  = 1.0f/(9.0f*128.0f);
    const float GSC = 1.0f/16384.0f;
    if (t < 64) {
        const int row = t >> 4, q = t & 15;
        const float4 s0 = consacc[0][row][q], s1 = consacc[1][row][q];
        const float4 s2 = consacc[2][row][q], s3 = consacc[3][row][q];
        float4 s;
        s.x = ((s0.x+s1.x)+(s2.x+s3.x))*SC;
        s.y = ((s0.y+s1.y)+(s2.y+s3.y))*SC;
        s.z = ((s0.z+s1.z)+(s2.z+s3.z))*SC;
        s.w = ((s0.w+s1.w)+(s2.w+s3.w))*SC;
        reinterpret_cast<float4*>(scr)[(cg << 14) + (b << 10) + (r0 + row)*16 + q] = s;
    } else if (t < 68) {
        const int row = t - 64;
        const float g = (ghacc[0][row]+ghacc[1][row])+(ghacc[2][row]+ghacc[3][row]);
        scr[SCR_GHP + (b*NH + r0 + row)*8 + cg] = g * GSC;
    } else if (t >= 128 && t < 192) {
        const int w = t - 128;   // 0..63
        const float s = (gwacc[0][w]+gwacc[1][w])+(gwacc[2][w]+gwacc[3][w]);
        scr[SCR_GWP + (size_t)(b*NW + w)*128 + cg*16 + hg] = s * GSC;
    }
}

// 256 blocks (b, s: 4-row sixteenth of the plane): pre-stage gw/gh sums in
// LDS, then one f4-pixel per thread (t<64): sum 8 cons slices, sigmoid -> att.
__global__ __launch_bounds__(256) void k_att(float* __restrict__ ws,
                                             const float* __restrict__ scr,
                                             const float* __restrict__ pgw,
                                             const float* __restrict__ pgb) {
    __shared__ __align__(16) float sgw[64];
    __shared__ __align__(16) float sgh[4];
    const int t = threadIdx.x;
    const int s = blockIdx.x & 15;
    const int b = blockIdx.x >> 4;

    if (t < 64) {
        const float4* gp = reinterpret_cast<const float4*>(scr + SCR_GWP + (size_t)(b*NW + t)*128);
        float acc = 0.f;
        #pragma unroll
        for (int i = 0; i < 32; ++i) acc += sum4(gp[i]);
        sgw[t] = acc;
    } else if (t < 68) {
        const int r = s*4 + (t - 64);
        const float4* gp = reinterpret_cast<const float4*>(scr + SCR_GHP + (b*NH + r)*8);
        sgh[t-64] = sum4(gp[0]) + sum4(gp[1]);
    }
    __syncthreads();

    if (t < 64) {
        const int u = (b << 10) + (s << 6) + t;   // f4-pixel
        const float4* cp = reinterpret_cast<const float4*>(scr);
        float4 sm = {0.f,0.f,0.f,0.f};
        #pragma unroll
        for (int g = 0; g < 8; ++g) {
            const float4 vv = cp[(g << 14) + u];
            sm.x += vv.x; sm.y += vv.y; sm.z += vv.z; sm.w += vv.w;
        }
        const float ghv  = sgh[t >> 4];
        const float4 gwv = *reinterpret_cast<const float4*>(&sgw[(t & 15)*4]);
        const float gW = pgw[0], gB = pgb[0];

        float4 o;
        float z;
        z = gW*(ghv+gwv.x)*(1.f - fminf(fmaxf(sm.x,0.f),1.f)) + gB; o.x = 1.f/(1.f+expf(-z));
        z = gW*(ghv+gwv.y)*(1.f - fminf(fmaxf(sm.y,0.f),1.f)) + gB; o.y = 1.f/(1.f+expf(-z));
        z = gW*(ghv+gwv.z)*(1.f - fminf(fmaxf(sm.z,0.f),1.f)) + gB; o.z = 1.f/(1.f+expf(-z));
        z = gW*(ghv+gwv.w)*(1.f - fminf(fmaxf(sm.w,0.f),1.f)) + gB; o.w = 1.f/(1.f+expf(-z));
        reinterpret_cast<float4*>(ws + WS_ATT)[u] = o;
    }
}

__global__ __launch_bounds__(256) void k_apply(const float* __restrict__ x,
                                               const float* __restrict__ ws,
                                               float* __restrict__ out) {
    const float* att = ws + WS_ATT;
    const int total4 = NB*NC*NH*NW/4;   // 4,194,304
    const int stride = gridDim.x * blockDim.x;
    for (int i = blockIdx.x*blockDim.x + threadIdx.x; i < total4; i += stride) {
        const int w4 = i & 15;
        const int h  = (i >> 4) & 63;
        const int b  = i >> 18;
        const float4 xv = reinterpret_cast<const float4*>(x)[i];
        const float4 av = reinterpret_cast<const float4*>(att)[(b << 10) + (h << 4) + w4];
        float4 o;
        o.x = xv.x*av.x; o.y = xv.y*av.y; o.z = xv.z*av.z; o.w = xv.w*av.w;
        reinterpret_cast<float4*>(out)[i] = o;
    }
}

extern "C" void kernel_launch(void* const* d_in, const int* in_sizes, int n_in,
                              void* d_out, int out_size, void* d_ws, size_t ws_size,
                              hipStream_t stream) {
    const float* x   = (const float*)d_in[0];
    const float* dwh = (const float*)d_in[1];
    const float* dww = (const float*)d_in[2];
    const float* pgw = (const float*)d_in[3];
    const float* pgb = (const float*)d_in[4];
    float* out = (float*)d_out;
    float* ws  = (float*)d_ws;
    // d_out doubles as scratch (~2.6 MB of partials): written by k_reduce,
    // consumed by k_att, then fully overwritten by k_apply.
    float* scr = out;

    k_reduce<<<NB*8*16, 256, 0, stream>>>(x, dwh, dww, scr);
    k_att<<<256, 256, 0, stream>>>(ws, scr, pgw, pgb);
    k_apply<<<2048, 256, 0, stream>>>(x, ws, out);
}

// Round 14
// 43.700 us; speedup vs baseline: 1.1277x; 1.1277x over previous
//
#include <hip/hip_runtime.h>
#include <math.h>

#define NB 16
#define NC 256
#define NH 64
#define NW 64
#define HALF 128
#define PLANE (NH*NW)   // 4096

// ws: attention map only
#define WS_ATT 0              // NB*NH*NW = 65536 floats

// d_out scratch (floats), all plain stores:
#define SCR_CONS 0                   // 8 slices x [b][h][w] = 524288 floats
#define SCR_GHP  524288              // [b*64+h]*8 + cg : 8192 floats
#define SCR_GWP  (524288 + 8192)     // [b*64+w]*64 + cg*8+hg : 65536 floats

__device__ __forceinline__ float sum4(float4 v) { return (v.x+v.y)+(v.z+v.w); }

// R12-proven reduce: Block = (b, cg: 16 channel-pairs, hg: 8-row stripe).
// 1024 blocks. Wave v covers pairs cg*16+v*4..+3; lane = w4(4b)<<2 | pl(2b).
// Streaming: 10-iteration row loop, 2 independent float4 loads/iter, rolling
// 3-row product window in named regs, horizontal 3-tap via lane shuffles,
// pair-reduce via shfl_xor. ONE barrier. Plain-store partials, zero atomics.
__global__ __launch_bounds__(256) void k_reduce(const float* __restrict__ x,
                                                const float* __restrict__ dwh,
                                                const float* __restrict__ dww,
                                                float* __restrict__ scr) {
    __shared__ float  ew[256], eh[256];       // exp(weights)
    __shared__ float  wsum[8];
    __shared__ float4 consacc[4][8][16];      // per-wave cons rows, 8 KB
    __shared__ float  ghacc[4][8];
    __shared__ float  gwacc[4][64];

    const int t    = threadIdx.x;
    const int v    = t >> 6;        // wave 0..3
    const int lane = t & 63;
    const int pl   = lane & 3;      // channel-pair lane
    const int w4   = lane >> 2;     // float4 col 0..15

    const int blk = blockIdx.x;
    const int hg  = blk & 7;            // 8-row stripe
    const int cg  = (blk >> 3) & 7;     // 16-pair group
    const int b   = blk >> 6;
    const int r0  = hg << 3;            // first owned row

    // ---- prologue: softmax denominators
    {
        const float vw = dww[t], vh = dwh[t];
        const float evw = expf(vw), evh = expf(vh);
        ew[t] = evw; eh[t] = evh;
        float sw = evw, sh = evh;
        #pragma unroll
        for (int m = 1; m < 64; m <<= 1) { sw += __shfl_xor(sw, m); sh += __shfl_xor(sh, m); }
        if (lane == 0) { wsum[v] = sw; wsum[4+v] = sh; }
    }
    __syncthreads();
    const float invSw = 1.f/((wsum[0]+wsum[1])+(wsum[2]+wsum[3]));
    const float invSh = 1.f/((wsum[4]+wsum[5])+(wsum[6]+wsum[7]));

    const int   c1  = cg*16 + v*4 + pl;
    const float ww1 = ew[c1]*invSw, ww2 = ew[c1+HALF]*invSw;
    const float wh1 = eh[c1]*invSh, wh2 = eh[c1+HALF]*invSh;

    const float* p1 = x + ((size_t)(b*NC + c1))*PLANE + w4*4;
    const float* p2 = p1 + (size_t)HALF*PLANE;

    // rolling product window (named regs -> no scratch)
    float4 w0 = {0,0,0,0}, w1 = {0,0,0,0}, w2 = {0,0,0,0};
    float4 colacc = {0,0,0,0};

    #pragma unroll
    for (int j = 0; j < 10; ++j) {
        const int r = r0 - 1 + j;                   // row to load
        float4 p = {0.f,0.f,0.f,0.f};
        const bool live = (j == 0) ? (r >= 0) : ((j == 9) ? (r < 64) : true);
        if (live) {
            const float4 x1 = *reinterpret_cast<const float4*>(p1 + r*NW);
            const float4 x2 = *reinterpret_cast<const float4*>(p2 + r*NW);
            p.x = x1.x*x2.x; p.y = x1.y*x2.y; p.z = x1.z*x2.z; p.w = x1.w*x2.w;
            if (j >= 1 && j <= 8) {                 // owned rows: gh/gw
                float g = ww1*sum4(x1) + ww2*sum4(x2);
                g += __shfl_xor(g,1);  g += __shfl_xor(g,2);  g += __shfl_xor(g,4);
                g += __shfl_xor(g,8);  g += __shfl_xor(g,16); g += __shfl_xor(g,32);
                if (lane == 0) ghacc[v][j-1] = g;
                colacc.x += wh1*x1.x + wh2*x2.x;
                colacc.y += wh1*x1.y + wh2*x2.y;
                colacc.z += wh1*x1.z + wh2*x2.z;
                colacc.w += wh1*x1.w + wh2*x2.w;
            }
        }
        w0 = w1; w1 = w2; w2 = p;
        if (j >= 2) {                               // emit cons row r0+j-2
            float4 vs;
            vs.x = w0.x+w1.x+w2.x; vs.y = w0.y+w1.y+w2.y;
            vs.z = w0.z+w1.z+w2.z; vs.w = w0.w+w1.w+w2.w;
            float L = __shfl_up(vs.w, 4);
            float R = __shfl_down(vs.x, 4);
            if (w4 == 0)  L = 0.f;
            if (w4 == 15) R = 0.f;
            float4 c;
            c.x = fabsf(L    + vs.x + vs.y);
            c.y = fabsf(vs.x + vs.y + vs.z);
            c.z = fabsf(vs.y + vs.z + vs.w);
            c.w = fabsf(vs.z + vs.w + R);
            c.x += __shfl_xor(c.x,1); c.x += __shfl_xor(c.x,2);
            c.y += __shfl_xor(c.y,1); c.y += __shfl_xor(c.y,2);
            c.z += __shfl_xor(c.z,1); c.z += __shfl_xor(c.z,2);
            c.w += __shfl_xor(c.w,1); c.w += __shfl_xor(c.w,2);
            if (pl == 0) consacc[v][j-2][w4] = c;
        }
    }

    // gw: reduce over pairs, stage per wave
    colacc.x += __shfl_xor(colacc.x,1); colacc.x += __shfl_xor(colacc.x,2);
    colacc.y += __shfl_xor(colacc.y,1); colacc.y += __shfl_xor(colacc.y,2);
    colacc.z += __shfl_xor(colacc.z,1); colacc.z += __shfl_xor(colacc.z,2);
    colacc.w += __shfl_xor(colacc.w,1); colacc.w += __shfl_xor(colacc.w,2);
    if (pl == 0) {
        gwacc[v][w4*4+0] = colacc.x;
        gwacc[v][w4*4+1] = colacc.y;
        gwacc[v][w4*4+2] = colacc.z;
        gwacc[v][w4*4+3] = colacc.w;
    }
    __syncthreads();   // the ONE barrier

    // ---- epilogue: cross-wave sums, plain stores
    const float SC  = 1.0f/(9.0f*128.0f);
    const float GSC = 1.0f/16384.0f;
    if (t < 128) {
        const int row = t >> 4, q = t & 15;
        const float4 s0 = consacc[0][row][q], s1 = consacc[1][row][q];
        const float4 s2 = consacc[2][row][q], s3 = consacc[3][row][q];
        float4 s;
        s.x = ((s0.x+s1.x)+(s2.x+s3.x))*SC;
        s.y = ((s0.y+s1.y)+(s2.y+s3.y))*SC;
        s.z = ((s0.z+s1.z)+(s2.z+s3.z))*SC;
        s.w = ((s0.w+s1.w)+(s2.w+s3.w))*SC;
        reinterpret_cast<float4*>(scr)[(cg << 14) + (b << 10) + (r0 + row)*16 + q] = s;
    } else if (t < 136) {
        const int row = t - 128;
        const float g = (ghacc[0][row]+ghacc[1][row])+(ghacc[2][row]+ghacc[3][row]);
        scr[SCR_GHP + (b*NH + r0 + row)*8 + cg] = g * GSC;
    } else if (t < 200) {
        const int w = t - 136;   // 0..63
        const float s = (gwacc[0][w]+gwacc[1][w])+(gwacc[2][w]+gwacc[3][w]);
        scr[SCR_GWP + (size_t)(b*NW + w)*64 + cg*8 + hg] = s * GSC;
    }
}

// 256 blocks (b, s: 4-row sixteenth): pre-stage gw/gh sums in LDS, then one
// f4-pixel per thread (t<64): sum 8 cons slices, sigmoid -> att map.
__global__ __launch_bounds__(256) void k_att(float* __restrict__ ws,
                                             const float* __restrict__ scr,
                                             const float* __restrict__ pgw,
                                             const float* __restrict__ pgb) {
    __shared__ __align__(16) float sgw[64];
    __shared__ __align__(16) float sgh[4];
    const int t = threadIdx.x;
    const int s = blockIdx.x & 15;
    const int b = blockIdx.x >> 4;

    if (t < 64) {
        const float4* gp = reinterpret_cast<const float4*>(scr + SCR_GWP + (size_t)(b*NW + t)*64);
        float acc = 0.f;
        #pragma unroll
        for (int i = 0; i < 16; ++i) acc += sum4(gp[i]);
        sgw[t] = acc;
    } else if (t < 68) {
        const int r = s*4 + (t - 64);
        const float4* gp = reinterpret_cast<const float4*>(scr + SCR_GHP + (b*NH + r)*8);
        sgh[t-64] = sum4(gp[0]) + sum4(gp[1]);
    }
    __syncthreads();

    if (t < 64) {
        const int u = (b << 10) + (s << 6) + t;   // f4-pixel
        const float4* cp = reinterpret_cast<const float4*>(scr);
        float4 sm = {0.f,0.f,0.f,0.f};
        #pragma unroll
        for (int g = 0; g < 8; ++g) {
            const float4 vv = cp[(g << 14) + u];
            sm.x += vv.x; sm.y += vv.y; sm.z += vv.z; sm.w += vv.w;
        }
        const float ghv  = sgh[t >> 4];
        const float4 gwv = *reinterpret_cast<const float4*>(&sgw[(t & 15)*4]);
        const float gW = pgw[0], gB = pgb[0];

        float4 o;
        float z;
        z = gW*(ghv+gwv.x)*(1.f - fminf(fmaxf(sm.x,0.f),1.f)) + gB; o.x = 1.f/(1.f+expf(-z));
        z = gW*(ghv+gwv.y)*(1.f - fminf(fmaxf(sm.y,0.f),1.f)) + gB; o.y = 1.f/(1.f+expf(-z));
        z = gW*(ghv+gwv.z)*(1.f - fminf(fmaxf(sm.z,0.f),1.f)) + gB; o.z = 1.f/(1.f+expf(-z));
        z = gW*(ghv+gwv.w)*(1.f - fminf(fmaxf(sm.w,0.f),1.f)) + gB; o.w = 1.f/(1.f+expf(-z));
        reinterpret_cast<float4*>(ws + WS_ATT)[u] = o;
    }
}

__global__ __launch_bounds__(256) void k_apply(const float* __restrict__ x,
                                               const float* __restrict__ ws,
                                               float* __restrict__ out) {
    const float* att = ws + WS_ATT;
    const int total4 = NB*NC*NH*NW/4;   // 4,194,304
    const int stride = gridDim.x * blockDim.x;
    for (int i = blockIdx.x*blockDim.x + threadIdx.x; i < total4; i += stride) {
        const int w4 = i & 15;
        const int h  = (i >> 4) & 63;
        const int b  = i >> 18;
        const float4 xv = reinterpret_cast<const float4*>(x)[i];
        const float4 av = reinterpret_cast<const float4*>(att)[(b << 10) + (h << 4) + w4];
        float4 o;
        o.x = xv.x*av.x; o.y = xv.y*av.y; o.z = xv.z*av.z; o.w = xv.w*av.w;
        reinterpret_cast<float4*>(out)[i] = o;
    }
}

extern "C" void kernel_launch(void* const* d_in, const int* in_sizes, int n_in,
                              void* d_out, int out_size, void* d_ws, size_t ws_size,
                              hipStream_t stream) {
    const float* x   = (const float*)d_in[0];
    const float* dwh = (const float*)d_in[1];
    const float* dww = (const float*)d_in[2];
    const float* pgw = (const float*)d_in[3];
    const float* pgb = (const float*)d_in[4];
    float* out = (float*)d_out;
    float* ws  = (float*)d_ws;
    // d_out doubles as scratch (~2.3 MB of partials): written by k_reduce,
    // consumed by k_att, then fully overwritten by k_apply.
    float* scr = out;

    k_reduce<<<NB*8*8, 256, 0, stream>>>(x, dwh, dww, scr);
    k_att<<<256, 256, 0, stream>>>(ws, scr, pgw, pgb);
    k_apply<<<2048, 256, 0, stream>>>(x, ws, out);
}